// Round 10
// baseline (562.844 us; speedup 1.0000x reference)
//
#include <hip/hip_runtime.h>
#include <stdint.h>

#define NTOK 8192
#define CAP  1280
#define NEXP 32

typedef __bf16 bf16x8 __attribute__((ext_vector_type(8)));
typedef float f32x16 __attribute__((ext_vector_type(16)));
typedef unsigned short u16;

__device__ __forceinline__ u16 f2bf(float f) {
  unsigned u = __builtin_bit_cast(unsigned, f);
  u = (u + 0x7fffu + ((u >> 16) & 1u)) >> 16;
  return (u16)u;
}
__device__ __forceinline__ float bf2f(u16 h) {
  return __builtin_bit_cast(float, ((unsigned)h) << 16);
}

__device__ __forceinline__ void gload16(const void* g, void* l) {
  __builtin_amdgcn_global_load_lds(
      (const __attribute__((address_space(1))) void*)g,
      (__attribute__((address_space(3))) void*)l, 16, 0, 0);
}

// -------- transpose+convert 1024x1024 fp32 -> bf16, all weights in one ----
// 64(rows)x32(cols) tiles; float4 reads; uint4 (8xbf16) packed writes.
__global__ __launch_bounds__(256) void tconv_all_kernel(
    const float* __restrict__ w1, const float* __restrict__ w3,
    const float* __restrict__ w2, const float* __restrict__ sw1,
    const float* __restrict__ sw3, const float* __restrict__ sw2,
    u16* __restrict__ w1t, u16* __restrict__ w3t, u16* __restrict__ w2t,
    u16* __restrict__ sw1t, u16* __restrict__ sw3t, u16* __restrict__ sw2t) {
  __shared__ float tile[64][33];
  const int z = blockIdx.z;
  const float* src;
  u16* dst;
  if (z < 32)      { src = w1 + (size_t)z * 1048576;        dst = w1t + (size_t)z * 1048576; }
  else if (z < 64) { src = w3 + (size_t)(z - 32) * 1048576; dst = w3t + (size_t)(z - 32) * 1048576; }
  else if (z < 96) { src = w2 + (size_t)(z - 64) * 1048576; dst = w2t + (size_t)(z - 64) * 1048576; }
  else if (z == 96){ src = sw1; dst = sw1t; }
  else if (z == 97){ src = sw3; dst = sw3t; }
  else             { src = sw2; dst = sw2t; }
  const int r0 = blockIdx.x * 64, c0 = blockIdx.y * 32;
  const int tid = threadIdx.x;
#pragma unroll
  for (int p = 0; p < 2; ++p) {
    int row = p * 32 + (tid >> 3);
    int c4 = (tid & 7) * 4;
    float4 v = *reinterpret_cast<const float4*>(&src[(size_t)(r0 + row) * 1024 + c0 + c4]);
    tile[row][c4 + 0] = v.x;
    tile[row][c4 + 1] = v.y;
    tile[row][c4 + 2] = v.z;
    tile[row][c4 + 3] = v.w;
  }
  __syncthreads();
  {
    int cc = tid >> 3;
    int k8 = (tid & 7) * 8;
    unsigned w[4];
#pragma unroll
    for (int j = 0; j < 4; ++j) {
      unsigned lo = f2bf(tile[k8 + 2 * j][cc]);
      unsigned hi = f2bf(tile[k8 + 2 * j + 1][cc]);
      w[j] = lo | (hi << 16);
    }
    uint4 o = {w[0], w[1], w[2], w[3]};
    *reinterpret_cast<uint4*>(&dst[(size_t)(c0 + cc) * 1024 + r0 + k8]) = o;
  }
}

// ------- gating: one block per token; also emits xb (bf16 x) as by-product
__global__ __launch_bounds__(256) void gate_kernel(const float* __restrict__ x,
                                                   const float* __restrict__ wg,
                                                   int* __restrict__ gidx,
                                                   float* __restrict__ gw,
                                                   u16* __restrict__ xb) {
  const int t = blockIdx.x;
  __shared__ float xl[1024];
  __shared__ float logits[32];
  const int tid = threadIdx.x;
  float4 xv0 = reinterpret_cast<const float4*>(x + (size_t)t * 1024)[tid];
  reinterpret_cast<float4*>(xl)[tid] = xv0;
  {
    uint2 o;
    o.x = (unsigned)f2bf(xv0.x) | ((unsigned)f2bf(xv0.y) << 16);
    o.y = (unsigned)f2bf(xv0.z) | ((unsigned)f2bf(xv0.w) << 16);
    reinterpret_cast<uint2*>(xb)[t * 256 + tid] = o;
  }
  __syncthreads();
  const int e = tid >> 3, p = tid & 7;
  const float4* wrow = reinterpret_cast<const float4*>(wg + (size_t)e * 1024);
  const float4* xv4 = reinterpret_cast<const float4*>(xl);
  float s = 0.f;
#pragma unroll
  for (int i = 0; i < 32; ++i) {
    int c = p + 8 * i;
    float4 xv = xv4[c];
    float4 wv = wrow[c];
    s += xv.x * wv.x + xv.y * wv.y + xv.z * wv.z + xv.w * wv.w;
  }
  s += __shfl_xor(s, 1);
  s += __shfl_xor(s, 2);
  s += __shfl_xor(s, 4);
  if (p == 0) logits[e] = s;
  __syncthreads();
  if (tid == 0) {
    float m = logits[0];
#pragma unroll
    for (int i = 1; i < 32; ++i) m = fmaxf(m, logits[i]);
    float sum = 0.f;
#pragma unroll
    for (int i = 0; i < 32; ++i) sum += expf(logits[i] - m);
    float gm[8];
#pragma unroll
    for (int g = 0; g < 8; ++g) {
      float v = logits[4 * g];
      v = fmaxf(v, logits[4 * g + 1]);
      v = fmaxf(v, logits[4 * g + 2]);
      v = fmaxf(v, logits[4 * g + 3]);
      gm[g] = v;
    }
    unsigned gkeep = 0;
    for (int it = 0; it < 4; ++it) {
      float best = -3.4e38f; int bg = 0;
#pragma unroll
      for (int g = 0; g < 8; ++g) {
        bool ok = !((gkeep >> g) & 1u);
        if (ok && gm[g] > best) { best = gm[g]; bg = g; }
      }
      gkeep |= 1u << bg;
    }
    unsigned allow = 0;
#pragma unroll
    for (int g = 0; g < 8; ++g)
      if ((gkeep >> g) & 1u) allow |= 0xFu << (4 * g);
    unsigned taken = 0;
    float wsum = 0.f;
    int ids[4]; float wv[4];
    for (int sIt = 0; sIt < 4; ++sIt) {
      float best = -3.4e38f; int be = 0;
#pragma unroll
      for (int i = 0; i < 32; ++i) {
        bool ok = ((allow >> i) & 1u) && !((taken >> i) & 1u);
        float v = logits[i];
        if (ok && v > best) { best = v; be = i; }
      }
      taken |= 1u << be;
      ids[sIt] = be;
      float wq = expf(logits[be] - m) / sum;
      wv[sIt] = wq;
      wsum += wq;
    }
    float inv = 1.f / (wsum + 1e-9f);
#pragma unroll
    for (int sIt = 0; sIt < 4; ++sIt) {
      gidx[t * 4 + sIt] = ids[sIt];
      gw[t * 4 + sIt] = wv[sIt] * inv;
    }
  }
}

// ------- rank/dispatch: one block per expert, 1024 threads (init fused) ----
__global__ __launch_bounds__(1024) void rank_kernel(const int* __restrict__ gidx,
                                                    const float* __restrict__ gw,
                                                    int* __restrict__ buf_tok,
                                                    float* __restrict__ buf_w,
                                                    int* __restrict__ cnt,
                                                    int* __restrict__ tslot) {
  const int e = blockIdx.x;
  const int tid = threadIdx.x, wid = tid >> 6, lane = tid & 63;
  __shared__ int wtot[16];
  for (int i = tid; i < CAP; i += 1024) {
    buf_tok[e * CAP + i] = -1;
    buf_w[e * CAP + i] = 0.f;
  }
  __syncthreads();
  int base = 0;
  for (int j0 = 0; j0 < NTOK * 4; j0 += 1024) {
    int j = j0 + tid;
    bool match = (gidx[j] == e);
    unsigned long long mb = __ballot(match);
    if (lane == 0) wtot[wid] = __popcll(mb);
    __syncthreads();
    int woff = 0, btot = 0;
#pragma unroll
    for (int w = 0; w < 16; ++w) {
      int c = wtot[w];
      if (w < wid) woff += c;
      btot += c;
    }
    if (match) {
      int pos = base + woff + __popcll(mb & ((1ull << lane) - 1ull));
      if (pos < CAP) {
        buf_tok[e * CAP + pos] = j >> 2;
        buf_w[e * CAP + pos] = gw[j];
        tslot[j] = e * CAP + pos;
      } else {
        tslot[j] = -1;
      }
    }
    base += btot;
    __syncthreads();
  }
  if (tid == 0) cnt[e] = (base < CAP) ? base : CAP;
}

// ============ up-proj v11: 32x32x16 MFMA, one barrier per K-tile ==========
// v10 schedule with the 32x32x16_bf16 shape: 15% less matrix-pipe time per
// FLOP (m119: 2495 vs 2176 TF) and half the MFMA issue count; LDS traffic
// identical (same tile area x K). Operand map (analogy with working 16x16
// code): lane holds A[row=lane&31][k=8*(lane>>5)+j] -> b128 at 16B-slot
// W = ks*2 + (lane>>5). C/D map (m74/m101): col=lane&31,
// row=(reg&3)+8*(reg>>2)+4*(lane>>5). Swizzle/staging unchanged.
#define UP_RDB(BV, KS)                                                           \
  BV[0] = b1frag32(cur, 0, KS);                                                  \
  BV[1] = b3frag32(cur, 0, KS);                                                  \
  BV[2] = b1frag32(cur, 1, KS);                                                  \
  BV[3] = b3frag32(cur, 1, KS);

#define UP_MM(KS, BV)                                                                             \
  __builtin_amdgcn_s_setprio(1);                                                                  \
  _Pragma("unroll")                                                                               \
  for (int ms = 0; ms < 2; ++ms)                                                                  \
    _Pragma("unroll")                                                                             \
    for (int ns = 0; ns < 2; ++ns) {                                                              \
      acc1[ms][ns] = __builtin_amdgcn_mfma_f32_32x32x16_bf16(af[(KS) * 2 + ms], BV[ns * 2 + 0],   \
                                                             acc1[ms][ns], 0, 0, 0);              \
      acc3[ms][ns] = __builtin_amdgcn_mfma_f32_32x32x16_bf16(af[(KS) * 2 + ms], BV[ns * 2 + 1],   \
                                                             acc3[ms][ns], 0, 0, 0);              \
    }                                                                                             \
  __builtin_amdgcn_s_setprio(0);

__global__ __launch_bounds__(512) void up8_kernel(const u16* __restrict__ X,
                                                  const u16* __restrict__ w1t,
                                                  const u16* __restrict__ w3t,
                                                  const u16* __restrict__ sw1t,
                                                  const u16* __restrict__ sw3t,
                                                  u16* __restrict__ hs,
                                                  u16* __restrict__ he,
                                                  const int* __restrict__ btok,
                                                  const int* __restrict__ cnt) {
  extern __shared__ __align__(16) u16 lds_raw[];   // 2 x (A 32K + B1 16K + B3 16K) = 128KB
  const int tid = threadIdx.x, wid = tid >> 6, lane = tid & 63;
  const int bid = blockIdx.x;
  const int xcd = bid & 7, off = bid >> 3;   // off 0..191
  bool expert;
  int mt, nt, e = 0;
  const u16 *B1, *B3;
  u16* H;
  if (off < 160) {
    expert = true;
    int id = xcd * 160 + off;
    e = id / 40;
    int r = id % 40;
    mt = r % 5;
    nt = r / 5;
    if (mt * 256 >= cnt[e]) return;
    B1 = w1t + ((size_t)e << 20);
    B3 = w3t + ((size_t)e << 20);
    H = he + (size_t)(e * CAP + mt * 256) * 1024;
  } else {
    expert = false;
    int id = xcd * 32 + (off - 160);
    mt = id % 32;
    nt = id / 32;
    B1 = sw1t;
    B3 = sw3t;
    H = hs + (size_t)mt * 256 * 1024;
  }
  const int wr = wid >> 1, wc = wid & 1;

  const int srow = wid * 8 + (lane >> 3);
  const int swin = (((lane & 7) ^ (srow & 7)) << 3);

  const u16* aP[4];
#pragma unroll
  for (int j = 0; j < 4; ++j) {
    int row = mt * 256 + j * 64 + srow;
    int grow;
    if (expert) {
      int t0 = btok[e * CAP + row];
      grow = (t0 < 0) ? 0 : t0;
    } else {
      grow = row;
    }
    aP[j] = X + (size_t)grow * 1024 + swin;
  }
  const u16* b1P[2];
  const u16* b3P[2];
#pragma unroll
  for (int j = 0; j < 2; ++j) {
    int row = nt * 128 + j * 64 + srow;
    b1P[j] = B1 + (size_t)row * 1024 + swin;
    b3P[j] = B3 + (size_t)row * 1024 + swin;
  }

  auto ldsA  = [&](int b) { return lds_raw + b * 32768; };
  auto ldsB1 = [&](int b) { return lds_raw + b * 32768 + 16384; };
  auto ldsB3 = [&](int b) { return lds_raw + b * 32768 + 24576; };

  auto stageA = [&](int b, int kt) {
    u16* base = ldsA(b) + wid * 512;
#pragma unroll
    for (int j = 0; j < 4; ++j)
      gload16(aP[j] + kt * 64, base + j * 4096);
  };
  auto stageB = [&](int b, int kt) {
    u16* d1 = ldsB1(b) + wid * 512;
    u16* d3 = ldsB3(b) + wid * 512;
#pragma unroll
    for (int j = 0; j < 2; ++j) {
      gload16(b1P[j] + kt * 64, d1 + j * 4096);
      gload16(b3P[j] + kt * 64, d3 + j * 4096);
    }
  };

  // 32x32 frag reads: row = tilebase + (lane&31); 16B-slot W = ks*2+(lane>>5)
  auto afrag32 = [&](int c, int ms, int ks) -> bf16x8 {
    int r = wr * 64 + ms * 32 + (lane & 31);
    int W = ks * 2 + (lane >> 5);
    return *reinterpret_cast<const bf16x8*>(ldsA(c) + r * 64 + ((W ^ (r & 7)) << 3));
  };
  auto b1frag32 = [&](int c, int ns, int ks) -> bf16x8 {
    int r = wc * 64 + ns * 32 + (lane & 31);
    int W = ks * 2 + (lane >> 5);
    return *reinterpret_cast<const bf16x8*>(ldsB1(c) + r * 64 + ((W ^ (r & 7)) << 3));
  };
  auto b3frag32 = [&](int c, int ns, int ks) -> bf16x8 {
    int r = wc * 64 + ns * 32 + (lane & 31);
    int W = ks * 2 + (lane >> 5);
    return *reinterpret_cast<const bf16x8*>(ldsB3(c) + r * 64 + ((W ^ (r & 7)) << 3));
  };

  f32x16 acc1[2][2] = {};
  f32x16 acc3[2][2] = {};

  stageA(0, 0);
  stageB(0, 0);
  asm volatile("s_waitcnt vmcnt(0)" ::: "memory");
  __builtin_amdgcn_s_barrier();

  for (int kt = 0; kt < 16; ++kt) {
    const int cur = kt & 1;
    const bool pf = (kt + 1 < 16);
    bf16x8 af[8];
#pragma unroll
    for (int ks = 0; ks < 4; ++ks) {
      af[ks * 2 + 0] = afrag32(cur, 0, ks);
      af[ks * 2 + 1] = afrag32(cur, 1, ks);
    }
    bf16x8 bA[4], bB[4];
    UP_RDB(bA, 0)
    // phase 0: read B(ks=1) ahead; stage A(kt+1)
    UP_RDB(bB, 1)
    if (pf) stageA(cur ^ 1, kt + 1);
    UP_MM(0, bA)
    // phase 1: read B(ks=2) ahead; stage B(kt+1)
    UP_RDB(bA, 2)
    if (pf) stageB(cur ^ 1, kt + 1);
    UP_MM(1, bB)
    // phase 2: read B(ks=3) ahead
    UP_RDB(bB, 3)
    UP_MM(2, bA)
    // phase 3: drain + single K-end barrier
    UP_MM(3, bB)
    asm volatile("s_waitcnt vmcnt(0)" ::: "memory");
    __builtin_amdgcn_s_barrier();
  }

  // ---- epilogue: silu wave-local; 32x32 C/D map
  const int col0 = nt * 128 + wc * 64 + (lane & 31);
  const int row0 = wr * 64 + 4 * (lane >> 5);
#pragma unroll
  for (int ms = 0; ms < 2; ++ms)
#pragma unroll
    for (int ns = 0; ns < 2; ++ns)
#pragma unroll
      for (int reg = 0; reg < 16; ++reg) {
        int row = row0 + ms * 32 + (reg & 3) + 8 * (reg >> 2);
        int col = col0 + ns * 32;
        float v1 = acc1[ms][ns][reg];
        float h = (v1 / (1.f + __expf(-v1))) * acc3[ms][ns][reg];
        H[(size_t)row * 1024 + col] = f2bf(h);
      }
}

// ============ down-proj v11: 32x32x16 MFMA, one barrier per K-tile ========
#define DN_RDA(DST, KS)                                                          \
  DST[0] = Afrag32(cur, 0, KS);                                                  \
  DST[1] = Afrag32(cur, 1, KS);                                                  \
  DST[2] = Afrag32(cur, 2, KS);                                                  \
  DST[3] = Afrag32(cur, 3, KS);

#define DN_MM(KS, AV)                                                                             \
  __builtin_amdgcn_s_setprio(1);                                                                  \
  _Pragma("unroll")                                                                               \
  for (int ms = 0; ms < 4; ++ms)                                                                  \
    _Pragma("unroll")                                                                             \
    for (int ns = 0; ns < 2; ++ns)                                                                \
      acc[ms][ns] = __builtin_amdgcn_mfma_f32_32x32x16_bf16(AV[ms], bf[(KS) * 2 + ns],            \
                                                            acc[ms][ns], 0, 0, 0);               \
  __builtin_amdgcn_s_setprio(0);

__global__ __launch_bounds__(512) void down8_kernel(const u16* __restrict__ hs,
                                                    const u16* __restrict__ he,
                                                    const u16* __restrict__ sB,
                                                    const u16* __restrict__ eB,
                                                    float* __restrict__ Out,
                                                    u16* __restrict__ OutB,
                                                    const float* __restrict__ bw,
                                                    const int* __restrict__ cnt) {
  extern __shared__ __align__(16) u16 lds_raw[];   // 2 buf x (A,B) x 32KB = 128KB
  const int tid = threadIdx.x, wid = tid >> 6, lane = tid & 63;
  const int bid = blockIdx.x;
  const int xcd = bid & 7, off = bid >> 3;   // off 0..95
  bool expert;
  int mt, nt, e = 0;
  const u16 *Asrc, *Bsrc;
  if (off < 80) {
    expert = true;
    int id = xcd * 80 + off;
    e = id / 20;
    int r = id % 20;
    mt = r % 5;
    nt = r / 5;
    if (mt * 256 >= cnt[e]) return;
    Asrc = he + (size_t)e * CAP * 1024;
    Bsrc = eB + ((size_t)e << 20);
  } else {
    expert = false;
    int id = xcd * 16 + (off - 80);
    mt = id % 32;
    nt = id / 32;
    Asrc = hs;
    Bsrc = sB;
  }
  const int wr = wid >> 2, wc = wid & 3;

  const int srow = wid * 8 + (lane >> 3);
  const int sslot = lane & 7;
  const int swin = ((sslot ^ (srow & 7)) << 3);
  const u16* aS = Asrc + (size_t)(mt * 256 + srow) * 1024 + swin;
  const u16* bS = Bsrc + (size_t)(nt * 256 + srow) * 1024 + swin;

  auto ldsA = [&](int b) { return lds_raw + b * 32768; };
  auto ldsB = [&](int b) { return lds_raw + b * 32768 + 16384; };

  auto stageA = [&](int b, int kt) {
    u16* base = ldsA(b);
#pragma unroll
    for (int j = 0; j < 4; ++j)
      gload16(aS + (size_t)j * 64 * 1024 + kt * 64, base + (j * 64 + wid * 8) * 64);
  };
  auto stageB = [&](int b, int kt) {
    u16* base = ldsB(b);
#pragma unroll
    for (int j = 0; j < 4; ++j)
      gload16(bS + (size_t)j * 64 * 1024 + kt * 64, base + (j * 64 + wid * 8) * 64);
  };

  auto Afrag32 = [&](int c, int ms, int ks) -> bf16x8 {
    int r = wr * 128 + ms * 32 + (lane & 31);
    int W = ks * 2 + (lane >> 5);
    return *reinterpret_cast<const bf16x8*>(ldsA(c) + r * 64 + ((W ^ (r & 7)) << 3));
  };
  auto Bfrag32 = [&](int c, int ns, int ks) -> bf16x8 {
    int r = wc * 64 + ns * 32 + (lane & 31);
    int W = ks * 2 + (lane >> 5);
    return *reinterpret_cast<const bf16x8*>(ldsB(c) + r * 64 + ((W ^ (r & 7)) << 3));
  };

  f32x16 acc[4][2] = {};

  stageA(0, 0);
  stageB(0, 0);
  asm volatile("s_waitcnt vmcnt(0)" ::: "memory");
  __builtin_amdgcn_s_barrier();

  for (int kt = 0; kt < 16; ++kt) {
    const int cur = kt & 1;
    const bool pf = (kt + 1 < 16);
    bf16x8 bf[8];   // B resident: [ks*2+ns]
#pragma unroll
    for (int ks = 0; ks < 4; ++ks) {
      bf[ks * 2 + 0] = Bfrag32(cur, 0, ks);
      bf[ks * 2 + 1] = Bfrag32(cur, 1, ks);
    }
    bf16x8 aA[4], aB[4];
    DN_RDA(aA, 0)
    // phase 0: read A(ks=1) ahead; stage A(kt+1)
    DN_RDA(aB, 1)
    if (pf) stageA(cur ^ 1, kt + 1);
    DN_MM(0, aA)
    // phase 1: read A(ks=2) ahead; stage B(kt+1)
    DN_RDA(aA, 2)
    if (pf) stageB(cur ^ 1, kt + 1);
    DN_MM(1, aB)
    // phase 2: read A(ks=3) ahead
    DN_RDA(aB, 3)
    DN_MM(2, aA)
    // phase 3: drain + single K-end barrier
    DN_MM(3, aB)
    asm volatile("s_waitcnt vmcnt(0)" ::: "memory");
    __builtin_amdgcn_s_barrier();
  }

  // ---- epilogue: 32x32 C/D map
  const int lcol = lane & 31;
  const int lrow = 4 * (lane >> 5);
  const int ocol0 = nt * 256 + wc * 64 + lcol;
  if (expert) {
#pragma unroll
    for (int ms = 0; ms < 4; ++ms)
#pragma unroll
      for (int reg = 0; reg < 16; ++reg) {
        int row = mt * 256 + wr * 128 + ms * 32 + (reg & 3) + 8 * (reg >> 2) + lrow;
        int slot = e * CAP + row;
        float wgt = bw[slot];
#pragma unroll
        for (int ns = 0; ns < 2; ++ns)
          OutB[(size_t)slot * 1024 + ocol0 + ns * 32] = f2bf(acc[ms][ns][reg] * wgt);
      }
  } else {
#pragma unroll
    for (int ms = 0; ms < 4; ++ms)
#pragma unroll
      for (int reg = 0; reg < 16; ++reg) {
        int row = mt * 256 + wr * 128 + ms * 32 + (reg & 3) + 8 * (reg >> 2) + lrow;
#pragma unroll
        for (int ns = 0; ns < 2; ++ns)
          Out[(size_t)row * 1024 + ocol0 + ns * 32] = acc[ms][ns][reg];
      }
  }
}

// ---------------- combine: out[t] += sum_k oe[tslot[t,k]] ----------------
__global__ __launch_bounds__(256) void combine_kernel(const u16* __restrict__ oe,
                                                      const int* __restrict__ tslot,
                                                      float* __restrict__ out) {
  const int t = blockIdx.x;
  const int c = threadIdx.x;
  int s0 = tslot[t * 4 + 0], s1 = tslot[t * 4 + 1];
  int s2 = tslot[t * 4 + 2], s3 = tslot[t * 4 + 3];
  float4 v = reinterpret_cast<float4*>(out + (size_t)t * 1024)[c];
  auto addsl = [&](int s) {
    if (s >= 0) {
      uint2 q = reinterpret_cast<const uint2*>(oe + (size_t)s * 1024)[c];
      v.x += bf2f((u16)(q.x & 0xffff));
      v.y += bf2f((u16)(q.x >> 16));
      v.z += bf2f((u16)(q.y & 0xffff));
      v.w += bf2f((u16)(q.y >> 16));
    }
  };
  addsl(s0); addsl(s1); addsl(s2); addsl(s3);
  reinterpret_cast<float4*>(out + (size_t)t * 1024)[c] = v;
}

extern "C" void kernel_launch(void* const* d_in, const int* in_sizes, int n_in,
                              void* d_out, int out_size, void* d_ws, size_t ws_size,
                              hipStream_t stream) {
  const float* x   = (const float*)d_in[0];
  const float* wg  = (const float*)d_in[1];
  const float* w1  = (const float*)d_in[2];
  const float* w2  = (const float*)d_in[3];
  const float* w3  = (const float*)d_in[4];
  const float* sw1 = (const float*)d_in[5];
  const float* sw2 = (const float*)d_in[6];
  const float* sw3 = (const float*)d_in[7];
  float* out = (float*)d_out;

  char* p = (char*)d_ws;
  auto alloc = [&](size_t bytes) {
    char* q = p;
    p += (bytes + 255) & ~(size_t)255;
    return q;
  };
  u16* xb   = (u16*)alloc((size_t)NTOK * 1024 * 2);
  u16* w1t  = (u16*)alloc((size_t)NEXP * 1024 * 1024 * 2);
  u16* w3t  = (u16*)alloc((size_t)NEXP * 1024 * 1024 * 2);
  u16* w2t  = (u16*)alloc((size_t)NEXP * 1024 * 1024 * 2);
  u16* sw1t = (u16*)alloc((size_t)1024 * 1024 * 2);
  u16* sw3t = (u16*)alloc((size_t)1024 * 1024 * 2);
  u16* sw2t = (u16*)alloc((size_t)1024 * 1024 * 2);
  u16* hs   = (u16*)alloc((size_t)NTOK * 1024 * 2);
  u16* he   = (u16*)alloc((size_t)NEXP * CAP * 1024 * 2);
  int*   gidx = (int*)alloc((size_t)NTOK * 4 * 4);
  float* gww  = (float*)alloc((size_t)NTOK * 4 * 4);
  int*   btok = (int*)alloc((size_t)NEXP * CAP * 4);
  float* bww  = (float*)alloc((size_t)NEXP * CAP * 4);
  int*   cnt  = (int*)alloc((size_t)NEXP * 4);
  int*   tslot= (int*)alloc((size_t)NTOK * 4 * 4);
  // slot-output buffer overlays w1t/w3t (dead after up8_kernel):
  u16* oe = w1t;

  // 1. weight transposes (x-convert fused into gate)
  tconv_all_kernel<<<dim3(16, 32, 99), 256, 0, stream>>>(w1, w3, w2, sw1, sw3, sw2,
                                                         w1t, w3t, w2t, sw1t, sw3t, sw2t);
  // 2. gating (emits xb) + dispatch (slot-init fused into rank)
  gate_kernel<<<NTOK, 256, 0, stream>>>(x, wg, gidx, gww, xb);
  rank_kernel<<<NEXP, 1024, 0, stream>>>(gidx, gww, btok, bww, cnt, tslot);
  // 3. up (expert + shared, XCD-balanced, 128KB dynamic LDS)
  up8_kernel<<<1536, 512, 131072, stream>>>(xb, w1t, w3t, sw1t, sw3t, hs, he, btok, cnt);
  // 4. down (expert + shared, XCD-balanced, 128KB dynamic LDS)
  down8_kernel<<<768, 512, 131072, stream>>>(hs, he, sw2t, w2t, out, oe, bww, cnt);
  // 5. gather-combine expert contributions into out
  combine_kernel<<<NTOK, 256, 0, stream>>>(oe, tslot, out);
}

// Round 11
// 517.581 us; speedup vs baseline: 1.0875x; 1.0875x over previous
//
#include <hip/hip_runtime.h>
#include <stdint.h>

#define NTOK 8192
#define CAP  1280
#define NEXP 32

typedef __bf16 bf16x8 __attribute__((ext_vector_type(8)));
typedef float f32x4 __attribute__((ext_vector_type(4)));
typedef unsigned short u16;

__device__ __forceinline__ u16 f2bf(float f) {
  unsigned u = __builtin_bit_cast(unsigned, f);
  u = (u + 0x7fffu + ((u >> 16) & 1u)) >> 16;
  return (u16)u;
}
__device__ __forceinline__ float bf2f(u16 h) {
  return __builtin_bit_cast(float, ((unsigned)h) << 16);
}

__device__ __forceinline__ void gload16(const void* g, void* l) {
  __builtin_amdgcn_global_load_lds(
      (const __attribute__((address_space(1))) void*)g,
      (__attribute__((address_space(3))) void*)l, 16, 0, 0);
}

// -------- transpose+convert 1024x1024 fp32 -> bf16, all weights in one ----
// 64(rows)x32(cols) tiles; float4 reads; uint4 (8xbf16) packed writes.
__global__ __launch_bounds__(256) void tconv_all_kernel(
    const float* __restrict__ w1, const float* __restrict__ w3,
    const float* __restrict__ w2, const float* __restrict__ sw1,
    const float* __restrict__ sw3, const float* __restrict__ sw2,
    u16* __restrict__ w1t, u16* __restrict__ w3t, u16* __restrict__ w2t,
    u16* __restrict__ sw1t, u16* __restrict__ sw3t, u16* __restrict__ sw2t) {
  __shared__ float tile[64][33];
  const int z = blockIdx.z;
  const float* src;
  u16* dst;
  if (z < 32)      { src = w1 + (size_t)z * 1048576;        dst = w1t + (size_t)z * 1048576; }
  else if (z < 64) { src = w3 + (size_t)(z - 32) * 1048576; dst = w3t + (size_t)(z - 32) * 1048576; }
  else if (z < 96) { src = w2 + (size_t)(z - 64) * 1048576; dst = w2t + (size_t)(z - 64) * 1048576; }
  else if (z == 96){ src = sw1; dst = sw1t; }
  else if (z == 97){ src = sw3; dst = sw3t; }
  else             { src = sw2; dst = sw2t; }
  const int r0 = blockIdx.x * 64, c0 = blockIdx.y * 32;
  const int tid = threadIdx.x;
#pragma unroll
  for (int p = 0; p < 2; ++p) {
    int row = p * 32 + (tid >> 3);
    int c4 = (tid & 7) * 4;
    float4 v = *reinterpret_cast<const float4*>(&src[(size_t)(r0 + row) * 1024 + c0 + c4]);
    tile[row][c4 + 0] = v.x;
    tile[row][c4 + 1] = v.y;
    tile[row][c4 + 2] = v.z;
    tile[row][c4 + 3] = v.w;
  }
  __syncthreads();
  {
    int cc = tid >> 3;
    int k8 = (tid & 7) * 8;
    unsigned w[4];
#pragma unroll
    for (int j = 0; j < 4; ++j) {
      unsigned lo = f2bf(tile[k8 + 2 * j][cc]);
      unsigned hi = f2bf(tile[k8 + 2 * j + 1][cc]);
      w[j] = lo | (hi << 16);
    }
    uint4 o = {w[0], w[1], w[2], w[3]};
    *reinterpret_cast<uint4*>(&dst[(size_t)(c0 + cc) * 1024 + r0 + k8]) = o;
  }
}

// ------- gating: one block per token; also emits xb (bf16 x) as by-product
__global__ __launch_bounds__(256) void gate_kernel(const float* __restrict__ x,
                                                   const float* __restrict__ wg,
                                                   int* __restrict__ gidx,
                                                   float* __restrict__ gw,
                                                   u16* __restrict__ xb) {
  const int t = blockIdx.x;
  __shared__ float xl[1024];
  __shared__ float logits[32];
  const int tid = threadIdx.x;
  float4 xv0 = reinterpret_cast<const float4*>(x + (size_t)t * 1024)[tid];
  reinterpret_cast<float4*>(xl)[tid] = xv0;
  {
    uint2 o;
    o.x = (unsigned)f2bf(xv0.x) | ((unsigned)f2bf(xv0.y) << 16);
    o.y = (unsigned)f2bf(xv0.z) | ((unsigned)f2bf(xv0.w) << 16);
    reinterpret_cast<uint2*>(xb)[t * 256 + tid] = o;
  }
  __syncthreads();
  const int e = tid >> 3, p = tid & 7;
  const float4* wrow = reinterpret_cast<const float4*>(wg + (size_t)e * 1024);
  const float4* xv4 = reinterpret_cast<const float4*>(xl);
  float s = 0.f;
#pragma unroll
  for (int i = 0; i < 32; ++i) {
    int c = p + 8 * i;
    float4 xv = xv4[c];
    float4 wv = wrow[c];
    s += xv.x * wv.x + xv.y * wv.y + xv.z * wv.z + xv.w * wv.w;
  }
  s += __shfl_xor(s, 1);
  s += __shfl_xor(s, 2);
  s += __shfl_xor(s, 4);
  if (p == 0) logits[e] = s;
  __syncthreads();
  if (tid == 0) {
    float m = logits[0];
#pragma unroll
    for (int i = 1; i < 32; ++i) m = fmaxf(m, logits[i]);
    float sum = 0.f;
#pragma unroll
    for (int i = 0; i < 32; ++i) sum += expf(logits[i] - m);
    float gm[8];
#pragma unroll
    for (int g = 0; g < 8; ++g) {
      float v = logits[4 * g];
      v = fmaxf(v, logits[4 * g + 1]);
      v = fmaxf(v, logits[4 * g + 2]);
      v = fmaxf(v, logits[4 * g + 3]);
      gm[g] = v;
    }
    unsigned gkeep = 0;
    for (int it = 0; it < 4; ++it) {
      float best = -3.4e38f; int bg = 0;
#pragma unroll
      for (int g = 0; g < 8; ++g) {
        bool ok = !((gkeep >> g) & 1u);
        if (ok && gm[g] > best) { best = gm[g]; bg = g; }
      }
      gkeep |= 1u << bg;
    }
    unsigned allow = 0;
#pragma unroll
    for (int g = 0; g < 8; ++g)
      if ((gkeep >> g) & 1u) allow |= 0xFu << (4 * g);
    unsigned taken = 0;
    float wsum = 0.f;
    int ids[4]; float wv[4];
    for (int sIt = 0; sIt < 4; ++sIt) {
      float best = -3.4e38f; int be = 0;
#pragma unroll
      for (int i = 0; i < 32; ++i) {
        bool ok = ((allow >> i) & 1u) && !((taken >> i) & 1u);
        float v = logits[i];
        if (ok && v > best) { best = v; be = i; }
      }
      taken |= 1u << be;
      ids[sIt] = be;
      float wq = expf(logits[be] - m) / sum;
      wv[sIt] = wq;
      wsum += wq;
    }
    float inv = 1.f / (wsum + 1e-9f);
#pragma unroll
    for (int sIt = 0; sIt < 4; ++sIt) {
      gidx[t * 4 + sIt] = ids[sIt];
      gw[t * 4 + sIt] = wv[sIt] * inv;
    }
  }
}

// ------- rank/dispatch: one block per expert, 1024 threads (init fused) ----
__global__ __launch_bounds__(1024) void rank_kernel(const int* __restrict__ gidx,
                                                    const float* __restrict__ gw,
                                                    int* __restrict__ buf_tok,
                                                    float* __restrict__ buf_w,
                                                    int* __restrict__ cnt,
                                                    int* __restrict__ tslot) {
  const int e = blockIdx.x;
  const int tid = threadIdx.x, wid = tid >> 6, lane = tid & 63;
  __shared__ int wtot[16];
  for (int i = tid; i < CAP; i += 1024) {
    buf_tok[e * CAP + i] = -1;
    buf_w[e * CAP + i] = 0.f;
  }
  __syncthreads();
  int base = 0;
  for (int j0 = 0; j0 < NTOK * 4; j0 += 1024) {
    int j = j0 + tid;
    bool match = (gidx[j] == e);
    unsigned long long mb = __ballot(match);
    if (lane == 0) wtot[wid] = __popcll(mb);
    __syncthreads();
    int woff = 0, btot = 0;
#pragma unroll
    for (int w = 0; w < 16; ++w) {
      int c = wtot[w];
      if (w < wid) woff += c;
      btot += c;
    }
    if (match) {
      int pos = base + woff + __popcll(mb & ((1ull << lane) - 1ull));
      if (pos < CAP) {
        buf_tok[e * CAP + pos] = j >> 2;
        buf_w[e * CAP + pos] = gw[j];
        tslot[j] = e * CAP + pos;
      } else {
        tslot[j] = -1;
      }
    }
    base += btot;
    __syncthreads();
  }
  if (tid == 0) cnt[e] = (base < CAP) ? base : CAP;
}

// ============ up-proj v10: one barrier per K-tile (session best) ==========
// n-major phases, read-ahead, A resident. All reads in kt target stable
// buffer cur; stages target cur^1 (read by nobody during kt); stage-safety
// guaranteed by K-end barrier of kt-1 (reads lgkm-retired by consuming
// MFMAs), read-safety for kt+1 by vmcnt(0)+K-end barrier of kt. 16x16 MFMA
// keeps 16-lane row-groups -> row-XOR swizzle is conflict-free (32x32's
// 32-lane groups force 4-way conflicts on 128B rows: v11, 1.73e7).
#define UP_RDB(P1, P3, N)                                                        \
  P1[0] = b1frag(cur, N, 0);                                                     \
  P1[1] = b1frag(cur, N, 1);                                                     \
  P3[0] = b3frag(cur, N, 0);                                                     \
  P3[1] = b3frag(cur, N, 1);

#define UP_MM(N, P1, P3)                                                                          \
  __builtin_amdgcn_s_setprio(1);                                                                  \
  _Pragma("unroll")                                                                               \
  for (int m = 0; m < 4; ++m) {                                                                   \
    acc1[m][N] = __builtin_amdgcn_mfma_f32_16x16x32_bf16(af[2 * m], P1[0], acc1[m][N], 0, 0, 0);  \
    acc1[m][N] = __builtin_amdgcn_mfma_f32_16x16x32_bf16(af[2 * m + 1], P1[1], acc1[m][N], 0, 0, 0); \
    acc3[m][N] = __builtin_amdgcn_mfma_f32_16x16x32_bf16(af[2 * m], P3[0], acc3[m][N], 0, 0, 0);  \
    acc3[m][N] = __builtin_amdgcn_mfma_f32_16x16x32_bf16(af[2 * m + 1], P3[1], acc3[m][N], 0, 0, 0); \
  }                                                                                               \
  __builtin_amdgcn_s_setprio(0);

__global__ __launch_bounds__(512) void up8_kernel(const u16* __restrict__ X,
                                                  const u16* __restrict__ w1t,
                                                  const u16* __restrict__ w3t,
                                                  const u16* __restrict__ sw1t,
                                                  const u16* __restrict__ sw3t,
                                                  u16* __restrict__ hs,
                                                  u16* __restrict__ he,
                                                  const int* __restrict__ btok,
                                                  const int* __restrict__ cnt) {
  extern __shared__ __align__(16) u16 lds_raw[];   // 2 x (A 32K + B1 16K + B3 16K) = 128KB
  const int tid = threadIdx.x, wid = tid >> 6, lane = tid & 63;
  const int bid = blockIdx.x;
  const int xcd = bid & 7, off = bid >> 3;   // off 0..191
  bool expert;
  int mt, nt, e = 0;
  const u16 *B1, *B3;
  u16* H;
  if (off < 160) {
    expert = true;
    int id = xcd * 160 + off;
    e = id / 40;
    int r = id % 40;
    mt = r % 5;
    nt = r / 5;
    if (mt * 256 >= cnt[e]) return;
    B1 = w1t + ((size_t)e << 20);
    B3 = w3t + ((size_t)e << 20);
    H = he + (size_t)(e * CAP + mt * 256) * 1024;
  } else {
    expert = false;
    int id = xcd * 32 + (off - 160);
    mt = id % 32;
    nt = id / 32;
    B1 = sw1t;
    B3 = sw3t;
    H = hs + (size_t)mt * 256 * 1024;
  }
  const int wr = wid >> 1, wc = wid & 1;
  const int fr = lane & 15, fw = lane >> 4;

  const int srow = wid * 8 + (lane >> 3);
  const int swin = (((lane & 7) ^ (srow & 7)) << 3);

  const u16* aP[4];
#pragma unroll
  for (int j = 0; j < 4; ++j) {
    int row = mt * 256 + j * 64 + srow;
    int grow;
    if (expert) {
      int t0 = btok[e * CAP + row];
      grow = (t0 < 0) ? 0 : t0;
    } else {
      grow = row;
    }
    aP[j] = X + (size_t)grow * 1024 + swin;
  }
  const u16* b1P[2];
  const u16* b3P[2];
#pragma unroll
  for (int j = 0; j < 2; ++j) {
    int row = nt * 128 + j * 64 + srow;
    b1P[j] = B1 + (size_t)row * 1024 + swin;
    b3P[j] = B3 + (size_t)row * 1024 + swin;
  }

  auto ldsA  = [&](int b) { return lds_raw + b * 32768; };
  auto ldsB1 = [&](int b) { return lds_raw + b * 32768 + 16384; };
  auto ldsB3 = [&](int b) { return lds_raw + b * 32768 + 24576; };

  auto stageA = [&](int b, int kt) {
    u16* base = ldsA(b) + wid * 512;
#pragma unroll
    for (int j = 0; j < 4; ++j)
      gload16(aP[j] + kt * 64, base + j * 4096);
  };
  auto stageB = [&](int b, int kt) {
    u16* d1 = ldsB1(b) + wid * 512;
    u16* d3 = ldsB3(b) + wid * 512;
#pragma unroll
    for (int j = 0; j < 2; ++j) {
      gload16(b1P[j] + kt * 64, d1 + j * 4096);
      gload16(b3P[j] + kt * 64, d3 + j * 4096);
    }
  };

  auto afrag = [&](int c, int m, int ks) -> bf16x8 {
    int r = wr * 64 + m * 16 + fr;
    int W = ks * 4 + fw;
    return *reinterpret_cast<const bf16x8*>(ldsA(c) + r * 64 + ((W ^ (r & 7)) << 3));
  };
  auto b1frag = [&](int c, int n, int ks) -> bf16x8 {
    int r = wc * 64 + n * 16 + fr;
    int W = ks * 4 + fw;
    return *reinterpret_cast<const bf16x8*>(ldsB1(c) + r * 64 + ((W ^ (r & 7)) << 3));
  };
  auto b3frag = [&](int c, int n, int ks) -> bf16x8 {
    int r = wc * 64 + n * 16 + fr;
    int W = ks * 4 + fw;
    return *reinterpret_cast<const bf16x8*>(ldsB3(c) + r * 64 + ((W ^ (r & 7)) << 3));
  };

  f32x4 acc1[4][4] = {};
  f32x4 acc3[4][4] = {};

  stageA(0, 0);
  stageB(0, 0);
  asm volatile("s_waitcnt vmcnt(0)" ::: "memory");
  __builtin_amdgcn_s_barrier();

  for (int kt = 0; kt < 16; ++kt) {
    const int cur = kt & 1;
    const bool pf = (kt + 1 < 16);
    bf16x8 af[8];
#pragma unroll
    for (int m = 0; m < 4; ++m) {
      af[2 * m]     = afrag(cur, m, 0);
      af[2 * m + 1] = afrag(cur, m, 1);
    }
    bf16x8 bA1[2], bA3[2], bB1[2], bB3[2];
    UP_RDB(bA1, bA3, 0)
    // phase 0: read B[1] ahead; stage A(kt+1)
    UP_RDB(bB1, bB3, 1)
    if (pf) stageA(cur ^ 1, kt + 1);
    UP_MM(0, bA1, bA3)
    // phase 1: read B[2] ahead; stage B(kt+1)
    UP_RDB(bA1, bA3, 2)
    if (pf) stageB(cur ^ 1, kt + 1);
    UP_MM(1, bB1, bB3)
    // phase 2: read B[3] ahead
    UP_RDB(bB1, bB3, 3)
    UP_MM(2, bA1, bA3)
    // phase 3: drain + single K-end barrier
    UP_MM(3, bB1, bB3)
    asm volatile("s_waitcnt vmcnt(0)" ::: "memory");
    __builtin_amdgcn_s_barrier();
  }

  const int col0 = nt * 128 + wc * 64;
  const int row0 = wr * 64 + fw * 4;
#pragma unroll
  for (int m = 0; m < 4; ++m)
#pragma unroll
    for (int n = 0; n < 4; ++n)
#pragma unroll
      for (int ri = 0; ri < 4; ++ri) {
        int row = row0 + m * 16 + ri;
        int col = col0 + n * 16 + fr;
        float v1 = acc1[m][n][ri];
        float h = (v1 / (1.f + __expf(-v1))) * acc3[m][n][ri];
        H[(size_t)row * 1024 + col] = f2bf(h);
      }
}

// ============ down-proj v10: one barrier per K-tile =======================
#define DN_RDA(DST, M)                                                           \
  DST[0] = Afrag(cur, M, 0);                                                     \
  DST[1] = Afrag(cur, M, 1);                                                     \
  DST[2] = Afrag(cur, (M) + 1, 0);                                               \
  DST[3] = Afrag(cur, (M) + 1, 1);

#define DN_MM(M, AV)                                                                              \
  __builtin_amdgcn_s_setprio(1);                                                                  \
  _Pragma("unroll")                                                                               \
  for (int n = 0; n < 4; ++n) {                                                                   \
    acc[M][n] = __builtin_amdgcn_mfma_f32_16x16x32_bf16(AV[0], bfr[n][0], acc[M][n], 0, 0, 0);    \
    acc[M][n] = __builtin_amdgcn_mfma_f32_16x16x32_bf16(AV[1], bfr[n][1], acc[M][n], 0, 0, 0);    \
    acc[(M) + 1][n] = __builtin_amdgcn_mfma_f32_16x16x32_bf16(AV[2], bfr[n][0], acc[(M) + 1][n], 0, 0, 0); \
    acc[(M) + 1][n] = __builtin_amdgcn_mfma_f32_16x16x32_bf16(AV[3], bfr[n][1], acc[(M) + 1][n], 0, 0, 0); \
  }                                                                                               \
  __builtin_amdgcn_s_setprio(0);

__global__ __launch_bounds__(512) void down8_kernel(const u16* __restrict__ hs,
                                                    const u16* __restrict__ he,
                                                    const u16* __restrict__ sB,
                                                    const u16* __restrict__ eB,
                                                    float* __restrict__ Out,
                                                    u16* __restrict__ OutB,
                                                    const float* __restrict__ bw,
                                                    const int* __restrict__ cnt) {
  extern __shared__ __align__(16) u16 lds_raw[];   // 2 buf x (A,B) x 32KB = 128KB
  const int tid = threadIdx.x, wid = tid >> 6, lane = tid & 63;
  const int bid = blockIdx.x;
  const int xcd = bid & 7, off = bid >> 3;   // off 0..95
  bool expert;
  int mt, nt, e = 0;
  const u16 *Asrc, *Bsrc;
  if (off < 80) {
    expert = true;
    int id = xcd * 80 + off;
    e = id / 20;
    int r = id % 20;
    mt = r % 5;
    nt = r / 5;
    if (mt * 256 >= cnt[e]) return;
    Asrc = he + (size_t)e * CAP * 1024;
    Bsrc = eB + ((size_t)e << 20);
  } else {
    expert = false;
    int id = xcd * 16 + (off - 80);
    mt = id % 32;
    nt = id / 32;
    Asrc = hs;
    Bsrc = sB;
  }
  const int wr = wid >> 2, wc = wid & 3;

  const int srow = wid * 8 + (lane >> 3);
  const int sslot = lane & 7;
  const int swin = ((sslot ^ (srow & 7)) << 3);
  const u16* aS = Asrc + (size_t)(mt * 256 + srow) * 1024 + swin;
  const u16* bS = Bsrc + (size_t)(nt * 256 + srow) * 1024 + swin;

  auto ldsA = [&](int b) { return lds_raw + b * 32768; };
  auto ldsB = [&](int b) { return lds_raw + b * 32768 + 16384; };

  auto stageA = [&](int b, int kt) {
    u16* base = ldsA(b);
#pragma unroll
    for (int j = 0; j < 4; ++j)
      gload16(aS + (size_t)j * 64 * 1024 + kt * 64, base + (j * 64 + wid * 8) * 64);
  };
  auto stageB = [&](int b, int kt) {
    u16* base = ldsB(b);
#pragma unroll
    for (int j = 0; j < 4; ++j)
      gload16(bS + (size_t)j * 64 * 1024 + kt * 64, base + (j * 64 + wid * 8) * 64);
  };

  const int fr = lane & 15, fw = lane >> 4;
  auto Afrag = [&](int cur, int m, int ks) -> bf16x8 {
    int r = wr * 128 + m * 16 + fr;
    int W = ks * 4 + fw;
    return *reinterpret_cast<const bf16x8*>(ldsA(cur) + r * 64 + ((W ^ (r & 7)) << 3));
  };
  auto Bfrag = [&](int cur, int n, int ks) -> bf16x8 {
    int r = wc * 64 + n * 16 + fr;
    int W = ks * 4 + fw;
    return *reinterpret_cast<const bf16x8*>(ldsB(cur) + r * 64 + ((W ^ (r & 7)) << 3));
  };

  f32x4 acc[8][4] = {};

  stageA(0, 0);
  stageB(0, 0);
  asm volatile("s_waitcnt vmcnt(0)" ::: "memory");
  __builtin_amdgcn_s_barrier();

  for (int kt = 0; kt < 16; ++kt) {
    const int cur = kt & 1;
    const bool pf = (kt + 1 < 16);
    bf16x8 bfr[4][2];
#pragma unroll
    for (int n = 0; n < 4; ++n) {
      bfr[n][0] = Bfrag(cur, n, 0);
      bfr[n][1] = Bfrag(cur, n, 1);
    }
    bf16x8 aA[4], aB[4];
    DN_RDA(aA, 0)
    // phase 0: read A[2,3] ahead; stage A(kt+1)
    DN_RDA(aB, 2)
    if (pf) stageA(cur ^ 1, kt + 1);
    DN_MM(0, aA)
    // phase 1: read A[4,5] ahead; stage B(kt+1)
    DN_RDA(aA, 4)
    if (pf) stageB(cur ^ 1, kt + 1);
    DN_MM(2, aB)
    // phase 2: read A[6,7] ahead
    DN_RDA(aB, 6)
    DN_MM(4, aA)
    // phase 3: drain + single K-end barrier
    DN_MM(6, aB)
    asm volatile("s_waitcnt vmcnt(0)" ::: "memory");
    __builtin_amdgcn_s_barrier();
  }

  // ---- epilogue
  const int orow0 = mt * 256 + wr * 128 + fw * 4;
  const int ocol0 = nt * 256 + wc * 64;
  if (expert) {
#pragma unroll
    for (int m = 0; m < 8; ++m)
#pragma unroll
      for (int ri = 0; ri < 4; ++ri) {
        int row = orow0 + m * 16 + ri;
        int slot = e * CAP + row;
        float wgt = bw[slot];
#pragma unroll
        for (int n = 0; n < 4; ++n)
          OutB[(size_t)slot * 1024 + ocol0 + n * 16 + fr] = f2bf(acc[m][n][ri] * wgt);
      }
  } else {
#pragma unroll
    for (int m = 0; m < 8; ++m)
#pragma unroll
      for (int ri = 0; ri < 4; ++ri) {
        int row = orow0 + m * 16 + ri;
#pragma unroll
        for (int n = 0; n < 4; ++n)
          Out[(size_t)row * 1024 + ocol0 + n * 16 + fr] = acc[m][n][ri];
      }
  }
}

// ---------------- combine: out[t] += sum_k oe[tslot[t,k]] ----------------
__global__ __launch_bounds__(256) void combine_kernel(const u16* __restrict__ oe,
                                                      const int* __restrict__ tslot,
                                                      float* __restrict__ out) {
  const int t = blockIdx.x;
  const int c = threadIdx.x;
  int s0 = tslot[t * 4 + 0], s1 = tslot[t * 4 + 1];
  int s2 = tslot[t * 4 + 2], s3 = tslot[t * 4 + 3];
  float4 v = reinterpret_cast<float4*>(out + (size_t)t * 1024)[c];
  auto addsl = [&](int s) {
    if (s >= 0) {
      uint2 q = reinterpret_cast<const uint2*>(oe + (size_t)s * 1024)[c];
      v.x += bf2f((u16)(q.x & 0xffff));
      v.y += bf2f((u16)(q.x >> 16));
      v.z += bf2f((u16)(q.y & 0xffff));
      v.w += bf2f((u16)(q.y >> 16));
    }
  };
  addsl(s0); addsl(s1); addsl(s2); addsl(s3);
  reinterpret_cast<float4*>(out + (size_t)t * 1024)[c] = v;
}

extern "C" void kernel_launch(void* const* d_in, const int* in_sizes, int n_in,
                              void* d_out, int out_size, void* d_ws, size_t ws_size,
                              hipStream_t stream) {
  const float* x   = (const float*)d_in[0];
  const float* wg  = (const float*)d_in[1];
  const float* w1  = (const float*)d_in[2];
  const float* w2  = (const float*)d_in[3];
  const float* w3  = (const float*)d_in[4];
  const float* sw1 = (const float*)d_in[5];
  const float* sw2 = (const float*)d_in[6];
  const float* sw3 = (const float*)d_in[7];
  float* out = (float*)d_out;

  char* p = (char*)d_ws;
  auto alloc = [&](size_t bytes) {
    char* q = p;
    p += (bytes + 255) & ~(size_t)255;
    return q;
  };
  u16* xb   = (u16*)alloc((size_t)NTOK * 1024 * 2);
  u16* w1t  = (u16*)alloc((size_t)NEXP * 1024 * 1024 * 2);
  u16* w3t  = (u16*)alloc((size_t)NEXP * 1024 * 1024 * 2);
  u16* w2t  = (u16*)alloc((size_t)NEXP * 1024 * 1024 * 2);
  u16* sw1t = (u16*)alloc((size_t)1024 * 1024 * 2);
  u16* sw3t = (u16*)alloc((size_t)1024 * 1024 * 2);
  u16* sw2t = (u16*)alloc((size_t)1024 * 1024 * 2);
  u16* hs   = (u16*)alloc((size_t)NTOK * 1024 * 2);
  u16* he   = (u16*)alloc((size_t)NEXP * CAP * 1024 * 2);
  int*   gidx = (int*)alloc((size_t)NTOK * 4 * 4);
  float* gww  = (float*)alloc((size_t)NTOK * 4 * 4);
  int*   btok = (int*)alloc((size_t)NEXP * CAP * 4);
  float* bww  = (float*)alloc((size_t)NEXP * CAP * 4);
  int*   cnt  = (int*)alloc((size_t)NEXP * 4);
  int*   tslot= (int*)alloc((size_t)NTOK * 4 * 4);
  // slot-output buffer overlays w1t/w3t (dead after up8_kernel):
  u16* oe = w1t;

  // 1. weight transposes (x-convert fused into gate)
  tconv_all_kernel<<<dim3(16, 32, 99), 256, 0, stream>>>(w1, w3, w2, sw1, sw3, sw2,
                                                         w1t, w3t, w2t, sw1t, sw3t, sw2t);
  // 2. gating (emits xb) + dispatch (slot-init fused into rank)
  gate_kernel<<<NTOK, 256, 0, stream>>>(x, wg, gidx, gww, xb);
  rank_kernel<<<NEXP, 1024, 0, stream>>>(gidx, gww, btok, bww, cnt, tslot);
  // 3. up (expert + shared, XCD-balanced, 128KB dynamic LDS)
  up8_kernel<<<1536, 512, 131072, stream>>>(xb, w1t, w3t, sw1t, sw3t, hs, he, btok, cnt);
  // 4. down (expert + shared, XCD-balanced, 128KB dynamic LDS)
  down8_kernel<<<768, 512, 131072, stream>>>(hs, he, sw2t, w2t, out, oe, bww, cnt);
  // 5. gather-combine expert contributions into out
  combine_kernel<<<NTOK, 256, 0, stream>>>(oe, tslot, out);
}